// Round 10
// baseline (148.984 us; speedup 1.0000x reference)
//
#include <hip/hip_runtime.h>

// TotalVariationLoss: mean over (B,N,K) of squared distances to the K=8
// nearest neighbors (self excluded) of B*N 3D points. Only the SUM of each
// point's 8 smallest non-self d2 is needed.
//
// Round 10: (a) explicit ping-pong med3 insert (h -> g -> h across a pair
// of candidates) eliminates the ~8 v_mov/candidate that VGPR=20 regalloc
// forced in round 9; (b) QL=2 queries/lane doubles arithmetic per scalar
// candidate load and halves delivery events.

constexpr int B_    = 4;
constexpr int N_    = 8192;
constexpr int KNN   = 8;
constexpr int QL    = 2;               // queries per lane
constexpr int WAVES = 16;              // chunk-waves per block
constexpr int BLOCK = WAVES * 64;      // 1024 threads
constexpr int CHUNK = N_ / WAVES;      // 512 candidates per wave
constexpr int QG    = 64 * QL;         // 128 queries per block

#define CE(a, b) { const float _lo = fminf(a, b); b = fmaxf(a, b); a = _lo; }
#define MED3 __builtin_amdgcn_fmed3f

// insert dd into sorted src[0..7] -> dst[0..7] (independent med3 ops)
#define INS(dst, src, dd)                         \
    dst[0] = fminf(src[0], dd);                   \
    dst[1] = MED3(src[0], src[1], dd);            \
    dst[2] = MED3(src[1], src[2], dd);            \
    dst[3] = MED3(src[2], src[3], dd);            \
    dst[4] = MED3(src[3], src[4], dd);            \
    dst[5] = MED3(src[4], src[5], dd);            \
    dst[6] = MED3(src[5], src[6], dd);            \
    dst[7] = MED3(src[6], src[7], dd);

__global__ __launch_bounds__(256)
void prepack_kernel(const float* __restrict__ pts, float4* __restrict__ p4) {
    const int i = blockIdx.x * 256 + threadIdx.x;
    if (i < B_ * N_) {
        const float x = pts[i * 3 + 0], y = pts[i * 3 + 1], z = pts[i * 3 + 2];
        p4[i] = make_float4(x, y, z, fmaf(x, x, fmaf(y, y, z * z)));
    }
}

__global__ __launch_bounds__(BLOCK, 4)
void knn_tv_kernel(const float4* __restrict__ p4, float* __restrict__ out) {
    // [15*64 lanes][QL][KNN+1] floats: lane stride 18 -> 2-way conflict (free)
    __shared__ float lists[(WAVES - 1) * 64][QL][KNN + 1];   // 69.1 KiB

    const int tid   = threadIdx.x;
    const int lane  = tid & 63;
    const int w     = tid >> 6;               // wave id == chunk id
    const int g     = blockIdx.x;
    const int b     = g >> 6;                 // 64 query-groups per batch
    const int qbase = (g & 63) * QG;

    // wave-uniform candidate base -> s_load scalar broadcast
    const int chunk_off = __builtin_amdgcn_readfirstlane(b * N_ + w * CHUNK);
    const float4* __restrict__ cnd = p4 + chunk_off;

    const float4 q0 = p4[b * N_ + qbase + lane];        // coalesced
    const float4 q1 = p4[b * N_ + qbase + 64 + lane];
    const float a0x = -2.0f * q0.x, a0y = -2.0f * q0.y, a0z = -2.0f * q0.z;
    const float a1x = -2.0f * q1.x, a1y = -2.0f * q1.y, a1z = -2.0f * q1.z;

    float h0[KNN], g0[KNN], h1[KNN], g1[KNN];
#pragma unroll
    for (int k = 0; k < KNN; ++k) { h0[k] = 1e30f; h1[k] = 1e30f; }

    // candidates [c0p, c1p) contain this block's 128 queries (128-aligned)
    const int qsel = qbase - w * CHUNK;
    const bool own = (qsel >= 0) && (qsel < CHUNK);
    const int c0p  = own ? qsel : CHUNK;
    const int c1p  = own ? qsel + QG : CHUNK;

    // dist: seed chain with qsq (VGPR), add csq (SGPR) last -> 1 SGPR/VALU
    auto scan = [&](int lo, int hi, bool selfseg) {
#pragma unroll 2
        for (int i = lo; i < hi; i += 2) {     // pair of candidates: h->g->h
            const float4 sa = cnd[i];          // uniform -> s_load_dwordx4
            const float4 sb = cnd[i + 1];
            float da0 = fmaf(a0x, sa.x, fmaf(a0y, sa.y, fmaf(a0z, sa.z, q0.w))) + sa.w;
            float da1 = fmaf(a1x, sa.x, fmaf(a1y, sa.y, fmaf(a1z, sa.z, q1.w))) + sa.w;
            float db0 = fmaf(a0x, sb.x, fmaf(a0y, sb.y, fmaf(a0z, sb.z, q0.w))) + sb.w;
            float db1 = fmaf(a1x, sb.x, fmaf(a1y, sb.y, fmaf(a1z, sb.z, q1.w))) + sb.w;
            if (selfseg) {                     // exact self exclusion
                da0 = (lane == i - qsel)          ? 1e30f : da0;
                db0 = (lane == i + 1 - qsel)      ? 1e30f : db0;
                da1 = (lane == i - qsel - 64)     ? 1e30f : da1;
                db1 = (lane == i + 1 - qsel - 64) ? 1e30f : db1;
            }
            INS(g0, h0, da0)  INS(h0, g0, db0)
            INS(g1, h1, da1)  INS(h1, g1, db1)
        }
    };
    scan(0, c0p, false);
    scan(c0p, c1p, true);                      // self handled here only
    scan(c1p, CHUNK, false);

    // merge the 16 per-wave sorted lists (per query)
    if (w > 0) {
#pragma unroll
        for (int k = 0; k < KNN; ++k) {
            lists[(w - 1) * 64 + lane][0][k] = h0[k];
            lists[(w - 1) * 64 + lane][1][k] = h1[k];
        }
    }
    __syncthreads();
    if (w == 0) {
        for (int ww = 0; ww < WAVES - 1; ++ww) {
#pragma unroll
            for (int qi = 0; qi < QL; ++qi) {
                float e[KNN];
                float* h = qi ? h1 : h0;
#pragma unroll
                for (int k = 0; k < KNN; ++k) e[k] = lists[ww * 64 + lane][qi][k];
                // top-8 of two sorted lists: min vs reversed -> bitonic cleanup
                float m0 = fminf(h[0], e[7]), m1 = fminf(h[1], e[6]);
                float m2 = fminf(h[2], e[5]), m3 = fminf(h[3], e[4]);
                float m4 = fminf(h[4], e[3]), m5 = fminf(h[5], e[2]);
                float m6 = fminf(h[6], e[1]), m7 = fminf(h[7], e[0]);
                CE(m0, m4) CE(m1, m5) CE(m2, m6) CE(m3, m7)
                CE(m0, m2) CE(m1, m3) CE(m4, m6) CE(m5, m7)
                CE(m0, m1) CE(m2, m3) CE(m4, m5) CE(m6, m7)
                h[0] = m0; h[1] = m1; h[2] = m2; h[3] = m3;
                h[4] = m4; h[5] = m5; h[6] = m6; h[7] = m7;
            }
        }
        float qsum = 0.0f;
#pragma unroll
        for (int k = 0; k < KNN; ++k) qsum += h0[k] + h1[k];   // 2 distinct queries
#pragma unroll
        for (int off = 32; off >= 1; off >>= 1) qsum += __shfl_xor(qsum, off, 64);
        if (lane == 0)
            atomicAdd(out, qsum * (1.0f / ((float)B_ * N_ * KNN)));
    }
}

extern "C" void kernel_launch(void* const* d_in, const int* in_sizes, int n_in,
                              void* d_out, int out_size, void* d_ws, size_t ws_size,
                              hipStream_t stream) {
    const float* pts = (const float*)d_in[0];
    float* out = (float*)d_out;
    float4* p4 = (float4*)d_ws;               // 4*8192*16 = 512 KiB scratch

    hipMemsetAsync(out, 0, (size_t)out_size * sizeof(float), stream);
    prepack_kernel<<<(B_ * N_ + 255) / 256, 256, 0, stream>>>(pts, p4);
    knn_tv_kernel<<<B_ * (N_ / QG), BLOCK, 0, stream>>>(p4, out);  // 256 blocks
}

// Round 11
// 135.970 us; speedup vs baseline: 1.0957x; 1.0957x over previous
//
#include <hip/hip_runtime.h>

// TotalVariationLoss: mean over (B,N,K) of squared distances to the K=8
// nearest neighbors (self excluded) of B*N 3D points. Only the SUM of each
// point's 8 smallest non-self d2 is needed.
//
// Round 11: delivery experiment. Round-6 compute structure (sort-8 +
// bitonic merge, measured best) unchanged; candidate delivery switched
// from wave-uniform s_load (SMEM) to block-staged LDS tile + uniform
// ds_read_b128 broadcast (zero VALU cost, LDS pipe ~2 cyc/candidate).
// Rationale: rounds 6/9/10 all measure ~2.3x static VALU issue demand
// across three different ALU bodies -> shared per-candidate s_load/lgkm
// chain is the suspect, not the ALU body.

constexpr int B_     = 4;
constexpr int N_     = 8192;
constexpr int KNN    = 8;
constexpr int WAVES  = 16;             // waves per block = slices per tile
constexpr int BLOCK  = WAVES * 64;     // 1024 threads
constexpr int TILE   = 1024;           // candidates staged per tile
constexpr int NTILES = N_ / TILE;      // 8
// per wave per tile: 64 candidates (slice w), over 8 tiles = 512 total

#define CE(a, b) { const float _lo = fminf(a, b); b = fmaxf(a, b); a = _lo; }

__global__ __launch_bounds__(256)
void prepack_kernel(const float* __restrict__ pts, float4* __restrict__ p4) {
    const int i = blockIdx.x * 256 + threadIdx.x;
    if (i < B_ * N_) {
        const float x = pts[i * 3 + 0], y = pts[i * 3 + 1], z = pts[i * 3 + 2];
        p4[i] = make_float4(x, y, z, fmaf(x, x, fmaf(y, y, z * z)));
    }
}

__global__ __launch_bounds__(BLOCK, 8)
void knn_tv_kernel(const float4* __restrict__ p4, float* __restrict__ out) {
    __shared__ float4 tile[TILE];                        // 16 KiB
    __shared__ float  lists[(WAVES - 1) * 64][KNN + 1];  // 33.75 KiB

    const int tid   = threadIdx.x;
    const int lane  = tid & 63;
    const int w     = tid >> 6;               // wave id == tile-slice id
    const int g     = blockIdx.x;
    const int b     = g >> 7;                 // 128 query-groups per batch
    const int qbase = (g & 127) << 6;

    const float4* __restrict__ base = p4 + b * N_;
    const float4 q  = base[qbase + lane];     // coalesced 16B/lane
    const float qsq = q.w;
    const float m2x = -2.0f * q.x, m2y = -2.0f * q.y, m2z = -2.0f * q.z;

    // the (tile, wave) pair whose slice is exactly [qbase, qbase+64)
    const int tself = qbase >> 10;            // qbase / TILE
    const int wself = (qbase & (TILE - 1)) >> 6;

    float h[KNN];                              // ascending, h[7] = worst
#pragma unroll
    for (int k = 0; k < KNN; ++k) h[k] = 1e30f;

    for (int t = 0; t < NTILES; ++t) {
        __syncthreads();                       // previous tile fully consumed
        tile[tid] = base[t * TILE + tid];      // 1 float4/thread, coalesced
        __syncthreads();

        const float4* __restrict__ slice = &tile[w * 64];
        const bool selfseg = (t == tself) && (w == wself);

        auto do_group = [&](int gg, bool fix) {
            const float4* gp = slice + gg * 8;
            float d[8];
#pragma unroll
            for (int j = 0; j < 8; ++j) {
                const float4 s = gp[j];        // uniform addr -> LDS broadcast
                float dd = fmaf(m2x, s.x, fmaf(m2y, s.y, fmaf(m2z, s.z, qsq + s.w)));
                if (fix) dd = (lane == gg * 8 + j) ? 1e30f : dd;   // self
                d[j] = dd;
            }
            // Batcher odd-even sort-8, ascending (19 CE, depth 6)
            CE(d[0], d[1]) CE(d[2], d[3]) CE(d[4], d[5]) CE(d[6], d[7])
            CE(d[0], d[2]) CE(d[1], d[3]) CE(d[4], d[6]) CE(d[5], d[7])
            CE(d[1], d[2]) CE(d[5], d[6])
            CE(d[0], d[4]) CE(d[1], d[5]) CE(d[2], d[6]) CE(d[3], d[7])
            CE(d[2], d[4]) CE(d[3], d[5])
            CE(d[1], d[2]) CE(d[3], d[4]) CE(d[5], d[6])
            // top-8 of h ∪ d: elementwise min vs reversed d -> bitonic
            float m0 = fminf(h[0], d[7]), m1 = fminf(h[1], d[6]);
            float m2 = fminf(h[2], d[5]), m3 = fminf(h[3], d[4]);
            float m4 = fminf(h[4], d[3]), m5 = fminf(h[5], d[2]);
            float m6 = fminf(h[6], d[1]), m7 = fminf(h[7], d[0]);
            // bitonic cleanup -> ascending (12 CE)
            CE(m0, m4) CE(m1, m5) CE(m2, m6) CE(m3, m7)
            CE(m0, m2) CE(m1, m3) CE(m4, m6) CE(m5, m7)
            CE(m0, m1) CE(m2, m3) CE(m4, m5) CE(m6, m7)
            h[0] = m0; h[1] = m1; h[2] = m2; h[3] = m3;
            h[4] = m4; h[5] = m5; h[6] = m6; h[7] = m7;
        };

        if (selfseg) {
#pragma unroll 2
            for (int gg = 0; gg < 8; ++gg) do_group(gg, true);
        } else {
#pragma unroll 2
            for (int gg = 0; gg < 8; ++gg) do_group(gg, false);
        }
    }

    // merge the 16 per-wave sorted lists (per query = per lane)
    if (w > 0) {
#pragma unroll
        for (int k = 0; k < KNN; ++k) lists[(w - 1) * 64 + lane][k] = h[k];
    }
    __syncthreads();
    if (w == 0) {
        for (int ww = 0; ww < WAVES - 1; ++ww) {
            float e[KNN];
#pragma unroll
            for (int k = 0; k < KNN; ++k) e[k] = lists[ww * 64 + lane][k];
            float m0 = fminf(h[0], e[7]), m1 = fminf(h[1], e[6]);
            float m2 = fminf(h[2], e[5]), m3 = fminf(h[3], e[4]);
            float m4 = fminf(h[4], e[3]), m5 = fminf(h[5], e[2]);
            float m6 = fminf(h[6], e[1]), m7 = fminf(h[7], e[0]);
            CE(m0, m4) CE(m1, m5) CE(m2, m6) CE(m3, m7)
            CE(m0, m2) CE(m1, m3) CE(m4, m6) CE(m5, m7)
            CE(m0, m1) CE(m2, m3) CE(m4, m5) CE(m6, m7)
            h[0] = m0; h[1] = m1; h[2] = m2; h[3] = m3;
            h[4] = m4; h[5] = m5; h[6] = m6; h[7] = m7;
        }
        float qsum = 0.0f;
#pragma unroll
        for (int k = 0; k < KNN; ++k) qsum += h[k];
#pragma unroll
        for (int off = 32; off >= 1; off >>= 1) qsum += __shfl_xor(qsum, off, 64);
        if (lane == 0)
            atomicAdd(out, qsum * (1.0f / ((float)B_ * N_ * KNN)));
    }
}

extern "C" void kernel_launch(void* const* d_in, const int* in_sizes, int n_in,
                              void* d_out, int out_size, void* d_ws, size_t ws_size,
                              hipStream_t stream) {
    const float* pts = (const float*)d_in[0];
    float* out = (float*)d_out;
    float4* p4 = (float4*)d_ws;               // 4*8192*16 = 512 KiB scratch

    hipMemsetAsync(out, 0, (size_t)out_size * sizeof(float), stream);
    prepack_kernel<<<(B_ * N_ + 255) / 256, 256, 0, stream>>>(pts, p4);
    knn_tv_kernel<<<B_ * (N_ / 64), BLOCK, 0, stream>>>(p4, out);  // 512 blocks
}